// Round 9
// baseline (195.214 us; speedup 1.0000x reference)
//
#include <hip/hip_runtime.h>
#include <hip/hip_bf16.h>

using bf16 = __hip_bfloat16;
typedef short bf16x8 __attribute__((ext_vector_type(8)));
typedef float f32x4 __attribute__((ext_vector_type(4)));

#define CB 2
#define CS 2048
#define CD 1024
#define CH 16
#define CKH 4
#define CHD 64
#define CREP 4
#define CNQ (CH*CHD)    // 1024
#define CNKV (CKH*CHD)  // 256
#define CM (CB*CS)      // 4096

__device__ __forceinline__ unsigned short f2bf(float f) {
  union { float f; unsigned int i; } c; c.f = f;
  unsigned int r = c.i + 0x7FFFu + ((c.i >> 16) & 1u);  // RNE
  return (unsigned short)(r >> 16);
}
__device__ __forceinline__ void gload_lds16(const void* g, void* l) {
  __builtin_amdgcn_global_load_lds(
      (const __attribute__((address_space(1))) void*)g,
      (__attribute__((address_space(3))) void*)l, 16, 0, 0);
}

// ---------------------------------------------------------------------------
// bf16 MFMA GEMM v2 (R8-proven): C[M,N] f32 = A[M,K](lda) · Bt[N,K]^T.
// 128x128, BK=32, dbuf LDS, counted vmcnt.
// ---------------------------------------------------------------------------
__global__ __launch_bounds__(256) void gemm_mfma_kernel(
    const bf16* __restrict__ A, const bf16* __restrict__ Bt,
    float* __restrict__ C, int Mm, int Nn, int Kk, int lda)
{
  __shared__ __align__(16) bf16 As[2][128 * 32];
  __shared__ __align__(16) bf16 Bs[2][128 * 32];
  const int tid = threadIdx.x;
  const int lane = tid & 63;
  const int l15 = lane & 15;
  const int g = lane >> 4;
  const int wid = tid >> 6;
  const int wr = (wid >> 1) * 64;
  const int wc = (wid & 1) * 64;
  const int m0 = blockIdx.x * 128;
  const int n0 = blockIdx.y * 128;

  f32x4 acc[4][4];
  #pragma unroll
  for (int i = 0; i < 4; ++i)
    #pragma unroll
    for (int j = 0; j < 4; ++j)
      acc[i][j] = (f32x4){0.f, 0.f, 0.f, 0.f};

  const int sr = tid >> 2;
  const int sc = (tid & 3) * 8;
  const bf16* aSrc = A + (size_t)(m0 + sr) * lda + sc;
  const bf16* bSrc = Bt + (size_t)(n0 + sr) * Kk + sc;
  const int sOff = (tid & 192) * 8;

#define GSTAGE(bi, k0) do {                                             \
    gload_lds16(aSrc + (k0),                     &As[bi][sOff]);        \
    gload_lds16(aSrc + 64 * (size_t)lda + (k0),  &As[bi][sOff + 2048]); \
    gload_lds16(bSrc + (k0),                     &Bs[bi][sOff]);        \
    gload_lds16(bSrc + 64 * (size_t)Kk + (k0),   &Bs[bi][sOff + 2048]); \
  } while (0)

  const int nt = Kk >> 5;
  int bi = 0;
  GSTAGE(0, 0);
  for (int t = 0; t < nt; ++t) {
    if (t + 1 < nt) {
      GSTAGE(bi ^ 1, (t + 1) * 32);
      asm volatile("s_waitcnt vmcnt(4)" ::: "memory");
    } else {
      asm volatile("s_waitcnt vmcnt(0)" ::: "memory");
    }
    __builtin_amdgcn_s_barrier();
    asm volatile("" ::: "memory");

    bf16x8 af[4], bfr[4];
    #pragma unroll
    for (int mt = 0; mt < 4; ++mt)
      af[mt] = *(const bf16x8*)&As[bi][(wr + mt * 16 + l15) * 32 + g * 8];
    #pragma unroll
    for (int nt2 = 0; nt2 < 4; ++nt2)
      bfr[nt2] = *(const bf16x8*)&Bs[bi][(wc + nt2 * 16 + l15) * 32 + g * 8];
    #pragma unroll
    for (int mt = 0; mt < 4; ++mt)
      #pragma unroll
      for (int nt2 = 0; nt2 < 4; ++nt2)
        acc[mt][nt2] = __builtin_amdgcn_mfma_f32_16x16x32_bf16(af[mt], bfr[nt2], acc[mt][nt2], 0, 0, 0);

    asm volatile("" ::: "memory");
    __builtin_amdgcn_s_barrier();
    bi ^= 1;
  }
#undef GSTAGE

  #pragma unroll
  for (int mt = 0; mt < 4; ++mt)
    #pragma unroll
    for (int r4 = 0; r4 < 4; ++r4) {
      const size_t row = (size_t)(m0 + wr + mt * 16 + 4 * g + r4);
      #pragma unroll
      for (int nt2 = 0; nt2 < 4; ++nt2)
        C[row * Nn + n0 + wc + nt2 * 16 + l15] = acc[mt][nt2][r4];
    }
}

// ---------------------------------------------------------------------------
__global__ void conv_x_kernel(const float* __restrict__ x, bf16* __restrict__ xb)
{
  int i = (blockIdx.x * 256 + threadIdx.x) * 8;
  float4 a = *(const float4*)&x[i];
  float4 b = *(const float4*)&x[i + 4];
  unsigned short* o = (unsigned short*)xb + i;
  *(ushort4*)o = make_ushort4(f2bf(a.x), f2bf(a.y), f2bf(a.z), f2bf(a.w));
  *(ushort4*)(o + 4) = make_ushort4(f2bf(b.x), f2bf(b.y), f2bf(b.z), f2bf(b.w));
}

// W[K][N] f32 -> Wt[N][K] bf16 (LDS-tiled 64x64 transpose + convert).
__global__ __launch_bounds__(256) void transpose_conv_kernel(
    const float* __restrict__ W, bf16* __restrict__ Wt, int Kk, int Nn)
{
  __shared__ float T[64][65];
  const int k0 = blockIdx.x * 64;
  const int n0 = blockIdx.y * 64;
  const int tid = threadIdx.x;
  const int lr = tid >> 4;
  const int lc = (tid & 15) * 4;
  #pragma unroll
  for (int i = 0; i < 4; ++i) {
    float4 v = *(const float4*)&W[(size_t)(k0 + lr + i * 16) * Nn + n0 + lc];
    T[lr + i * 16][lc + 0] = v.x;
    T[lr + i * 16][lc + 1] = v.y;
    T[lr + i * 16][lc + 2] = v.z;
    T[lr + i * 16][lc + 3] = v.w;
  }
  __syncthreads();
  const int rn = tid >> 3;
  const int ck = (tid & 7) * 8;
  #pragma unroll
  for (int i = 0; i < 2; ++i) {
    int nn = rn + i * 32;
    unsigned short u[8];
    #pragma unroll
    for (int e = 0; e < 8; ++e) u[e] = f2bf(T[ck + e][nn]);
    unsigned short* dst = (unsigned short*)Wt + (size_t)(n0 + nn) * Kk + k0 + ck;
    *(ushort4*)dst = make_ushort4(u[0], u[1], u[2], u[3]);
    *(ushort4*)(dst + 4) = make_ushort4(u[4], u[5], u[6], u[7]);
  }
}

// ---------------------------------------------------------------------------
// RoPE q from fused qkv buffer: qkv_f [B*S][1536], q at cols 0..1023.
__global__ void rope_q_kernel(const float* __restrict__ qf,
                              const float* __restrict__ fc,
                              const float* __restrict__ fs,
                              bf16* __restrict__ qb)
{
  int p = blockIdx.x * blockDim.x + threadIdx.x;
  int j = p & 31;
  int h = (p >> 5) & 15;
  int s = (p >> 9) & 2047;
  int b = p >> 20;
  const float* src = qf + (size_t)(b * CS + s) * 1536 + h * CHD + j * 2;
  float x0 = src[0], x1 = src[1];
  float c = fc[s * 32 + j], sn = fs[s * 32 + j];
  bf16* dst = qb + ((size_t)(b * CH + h) * CS + s) * CHD + j * 2;
  dst[0] = __float2bfloat16(x0 * c - x1 * sn);
  dst[1] = __float2bfloat16(x0 * sn + x1 * c);
}

// RoPE k from fused qkv buffer: k at cols 1024..1279.
__global__ void rope_k_kernel(const float* __restrict__ kvf,
                              const float* __restrict__ fc,
                              const float* __restrict__ fs,
                              bf16* __restrict__ kb)
{
  int p = blockIdx.x * blockDim.x + threadIdx.x;
  int j = p & 31;
  int kh = (p >> 5) & 3;
  int s = (p >> 7) & 2047;
  int b = p >> 18;
  const float* src = kvf + (size_t)(b * CS + s) * 1536 + 1024 + kh * CHD + j * 2;
  float x0 = src[0], x1 = src[1];
  float c = fc[s * 32 + j], sn = fs[s * 32 + j];
  bf16* dst = kb + ((size_t)(b * CKH + kh) * CS + s) * CHD + j * 2;
  dst[0] = __float2bfloat16(x0 * c - x1 * sn);
  dst[1] = __float2bfloat16(x0 * sn + x1 * c);
}

// V transpose: qkv_f [B*S][1536] (v at cols 1280..1535) -> vt [B,KH,HD,S] bf16.
__global__ __launch_bounds__(256) void transpose_v_kernel(
    const float* __restrict__ kvf, bf16* __restrict__ vt)
{
  __shared__ float T[64][65];
  const int blk = blockIdx.x;
  const int st = blk & 31;
  const int kh = (blk >> 5) & 3;
  const int b = blk >> 7;
  const int tid = threadIdx.x;
  const int s = tid >> 2;
  const int d0 = (tid & 3) * 16;
  const float* src = kvf + ((size_t)(b * CS + st * 64 + s)) * 1536 + 1280 + kh * CHD + d0;
  #pragma unroll
  for (int i = 0; i < 4; ++i) {
    float4 v = *(const float4*)(src + i * 4);
    T[s][d0 + i * 4 + 0] = v.x;
    T[s][d0 + i * 4 + 1] = v.y;
    T[s][d0 + i * 4 + 2] = v.z;
    T[s][d0 + i * 4 + 3] = v.w;
  }
  __syncthreads();
  const int d = tid >> 2;
  const int s0 = (tid & 3) * 16;
  unsigned short* dst = (unsigned short*)vt +
      ((size_t)((b * CKH + kh) * CHD + d)) * CS + st * 64 + s0;
  #pragma unroll
  for (int i = 0; i < 2; ++i) {
    unsigned short u[8];
    #pragma unroll
    for (int e = 0; e < 8; ++e) u[e] = f2bf(T[s0 + i * 8 + e][d]);
    *(ushort4*)(dst + i * 8 + 0) = make_ushort4(u[0], u[1], u[2], u[3]);
    *(ushort4*)(dst + i * 8 + 4) = make_ushort4(u[4], u[5], u[6], u[7]);
  }
}

// ---------------------------------------------------------------------------
// MFMA flash attention v7: 8-wave blocks = 4 heads x 2 consecutive q-tiles
// (2jp, 2jp+1) sharing the K/V LDS tile stream (both diagonals in 64-tile jp).
// Grid = 256 blocks x 512 thr; 2 blocks/CU (LDS 69.6KB) = 4 waves/SIMD.
// Staging: ONE gload_lds16 each for K and V per tile (512 thr x 16B = 8KB),
// dbuf, counted vmcnt(2). P packed via v_cvt_pk_bf16_f32.
// ---------------------------------------------------------------------------
__global__ __launch_bounds__(512, 4) void flash_mfma_kernel(
    const bf16* __restrict__ qb, const bf16* __restrict__ kb,
    const bf16* __restrict__ vt, bf16* __restrict__ ob)
{
  __shared__ __align__(16) char arena[69632];
  char* KL = arena;                       // [2][8192]: K tile 64x(64 bf16)
  char* VL = arena + 16384;               // [2][8192]: V^T tile 64x(64 bf16)
  const int tid = threadIdx.x;            // 0..511
  const int lane = tid & 63;
  const int wid = tid >> 6;               // 0..7
  unsigned short* PLW = (unsigned short*)(arena + 32768) + wid * 2304; // [32][72]
  const int l15 = lane & 15;
  const int g = lane >> 4;
  const int blk = blockIdx.x;
  const int grp = blk & 7;                // b*4+kh (XCD spread)
  const int jp = 31 - (blk >> 3);         // LPT: longest pair first
  const int kh = grp & 3;
  const int b = grp >> 2;
  const int hw = wid & 3;                 // head within kv group
  const int qh = wid >> 2;                // which q-tile of the pair
  const int h = kh * CREP + hw;
  const int qt = 2 * jp + qh;
  const int N64 = jp + 1;                 // 64-key tiles (diag in tile jp)
  const float SC = 0.18033688f;           // 0.125 * log2(e)

  const bf16* qbase = qb + ((size_t)(b * CH + h) * CS + qt * 32) * CHD;
  const bf16* kbase = kb + (size_t)(b * CKH + kh) * CS * CHD;
  const bf16* vbase = vt + (size_t)(b * CKH + kh) * CHD * CS;  // [d][s]

  bf16x8 qf[2][2];
  #pragma unroll
  for (int qs = 0; qs < 2; ++qs)
    #pragma unroll
    for (int c = 0; c < 2; ++c)
      qf[qs][c] = *(const bf16x8*)(qbase + (qs * 16 + l15) * CHD + c * 32 + g * 8);

  bf16x8 ones;
  #pragma unroll
  for (int e = 0; e < 8; ++e) ones[e] = (short)0x3F80;  // bf16 1.0

  f32x4 oacc[2][4];
  f32x4 lacc[2];
  #pragma unroll
  for (int qs = 0; qs < 2; ++qs) {
    lacc[qs] = (f32x4){0.f, 0.f, 0.f, 0.f};
    #pragma unroll
    for (int dt = 0; dt < 4; ++dt)
      oacc[qs][dt] = (f32x4){0.f, 0.f, 0.f, 0.f};
  }
  float mrow[2] = {-1e30f, -1e30f};

  // staging: 512 threads x 16B = one full 8KB tile per gload.
  // thread t -> row t>>3, LDS chunk t&7 holds global chunk (t&7)^(row&7).
  const int slr = tid >> 3;               // 0..63
  const int scg = (tid & 7) ^ (slr & 7);
  const bf16* kstage = kbase + (size_t)slr * CHD + scg * 8;
  const bf16* vstage = vbase + (size_t)slr * CS + scg * 8;
  char* kdst = KL + wid * 1024;           // wave-uniform base (+lane*16 by HW)
  char* vdst = VL + wid * 1024;

#define STAGE(bi, t64) do {                                        \
    gload_lds16(kstage + (size_t)(t64) * 64 * CHD, kdst + (bi) * 8192); \
    gload_lds16(vstage + (t64) * 64,               vdst + (bi) * 8192); \
  } while (0)

  int bi = 0;
  STAGE(0, 0);
  for (int t = 0; t < N64; ++t) {
    if (t + 1 < N64) {
      STAGE(bi ^ 1, t + 1);
      asm volatile("s_waitcnt vmcnt(2)" ::: "memory");  // tile-t loads done
    } else {
      asm volatile("s_waitcnt vmcnt(0)" ::: "memory");
    }
    __builtin_amdgcn_s_barrier();
    asm volatile("" ::: "memory");

    const char* KB = KL + bi * 8192;
    const char* VB = VL + bi * 8192;
    bf16x8 kfr[4][2], vfr[4][2];
    #pragma unroll
    for (int kt = 0; kt < 4; ++kt) {
      int row = kt * 16 + l15;
      #pragma unroll
      for (int c = 0; c < 2; ++c)
        kfr[kt][c] = *(const bf16x8*)(KB + row * 128 + (((c * 4 + g) ^ (row & 7)) << 4));
    }
    #pragma unroll
    for (int dt = 0; dt < 4; ++dt) {
      int row = dt * 16 + l15;
      #pragma unroll
      for (int st = 0; st < 2; ++st)
        vfr[dt][st] = *(const bf16x8*)(VB + row * 128 + (((st * 4 + g) ^ (row & 7)) << 4));
    }

    // QK^T (swapped): S^T[k][q]
    f32x4 sacc[4][2];
    #pragma unroll
    for (int kt = 0; kt < 4; ++kt)
      #pragma unroll
      for (int qs = 0; qs < 2; ++qs)
        sacc[kt][qs] = (f32x4){0.f, 0.f, 0.f, 0.f};
    #pragma unroll
    for (int c = 0; c < 2; ++c)
      #pragma unroll
      for (int kt = 0; kt < 4; ++kt)
        #pragma unroll
        for (int qs = 0; qs < 2; ++qs)
          sacc[kt][qs] = __builtin_amdgcn_mfma_f32_16x16x32_bf16(kfr[kt][c], qf[qs][c], sacc[kt][qs], 0, 0, 0);

    const bool diag = (t == N64 - 1);
    #pragma unroll
    for (int qs = 0; qs < 2; ++qs) {
      float e[16];
      float pm = -1e30f;
      #pragma unroll
      for (int kt = 0; kt < 4; ++kt)
        #pragma unroll
        for (int r = 0; r < 4; ++r) {
          float v = sacc[kt][qs][r] * SC;
          if (diag) {
            int koff = kt * 16 + 4 * g + r;           // local key in tile jp
            if (koff > qh * 32 + qs * 16 + l15) v = -1e30f;
          }
          e[kt * 4 + r] = v;
          pm = fmaxf(pm, v);
        }
      if (__any(pm > mrow[qs] + 8.0f)) {       // slow path: exact rescale
        pm = fmaxf(pm, __shfl_xor(pm, 16, 64));
        pm = fmaxf(pm, __shfl_xor(pm, 32, 64));
        float nm = fmaxf(mrow[qs], pm);
        float corr = exp2f(mrow[qs] - nm);
        mrow[qs] = nm;
        lacc[qs] *= corr;
        #pragma unroll
        for (int dt = 0; dt < 4; ++dt) oacc[qs][dt] *= corr;
      }
      float pe[16];
      #pragma unroll
      for (int i = 0; i < 16; ++i)
        pe[i] = exp2f(e[i] - mrow[qs]);        // p <= 2^8
      #pragma unroll
      for (int kt = 0; kt < 4; ++kt) {
        unsigned int lo, hi;
        asm("v_cvt_pk_bf16_f32 %0, %1, %2" : "=v"(lo) : "v"(pe[kt * 4 + 0]), "v"(pe[kt * 4 + 1]));
        asm("v_cvt_pk_bf16_f32 %0, %1, %2" : "=v"(hi) : "v"(pe[kt * 4 + 2]), "v"(pe[kt * 4 + 3]));
        *(uint2*)&PLW[(qs * 16 + l15) * 72 + kt * 16 + 4 * g] = make_uint2(lo, hi);
      }
    }

    // PV + psum (same-wave LDS RAW)
    #pragma unroll
    for (int qs = 0; qs < 2; ++qs) {
      #pragma unroll
      for (int st = 0; st < 2; ++st) {
        bf16x8 pf = *(const bf16x8*)&PLW[(qs * 16 + l15) * 72 + st * 32 + g * 8];
        lacc[qs] = __builtin_amdgcn_mfma_f32_16x16x32_bf16(ones, pf, lacc[qs], 0, 0, 0);
        #pragma unroll
        for (int dt = 0; dt < 4; ++dt)
          oacc[qs][dt] = __builtin_amdgcn_mfma_f32_16x16x32_bf16(vfr[dt][st], pf, oacc[qs][dt], 0, 0, 0);
      }
    }

    asm volatile("" ::: "memory");
    __builtin_amdgcn_s_barrier();            // all reads of buf bi done
    bi ^= 1;
  }
#undef STAGE

  #pragma unroll
  for (int qs = 0; qs < 2; ++qs) {
    float inv = 1.0f / lacc[qs][0];
    int qg = qt * 32 + qs * 16 + l15;
    unsigned short* orow = (unsigned short*)ob + (size_t)(b * CS + qg) * CNQ + h * CHD;
    #pragma unroll
    for (int dt = 0; dt < 4; ++dt) {
      *(ushort4*)&orow[dt * 16 + 4 * g] =
          make_ushort4(f2bf(oacc[qs][dt][0] * inv), f2bf(oacc[qs][dt][1] * inv),
                       f2bf(oacc[qs][dt][2] * inv), f2bf(oacc[qs][dt][3] * inv));
    }
  }
}

// ---------------------------------------------------------------------------
extern "C" void kernel_launch(void* const* d_in, const int* in_sizes, int n_in,
                              void* d_out, int out_size, void* d_ws, size_t ws_size,
                              hipStream_t stream)
{
  const float* x  = (const float*)d_in[0];
  const float* wq = (const float*)d_in[1];
  const float* wk = (const float*)d_in[2];
  const float* wv = (const float*)d_in[3];
  const float* wo = (const float*)d_in[4];
  const float* fc = (const float*)d_in[5];
  const float* fs = (const float*)d_in[6];
  float* out = (float*)d_out;

  char* ws = (char*)d_ws;
  // workspace (peak 37.75MB, R8-proven layout):
  bf16*  x_b   = (bf16*)(ws);                // [0,8M)  dead after qkv GEMM
  float* qkv_f = (float*)(ws + 8388608);     // [8M,33.5M)
  bf16*  wqkvt = (bf16*)(ws + 33554432);     // [33.5M,36.7M) dead after GEMM
  bf16*  q_b   = (bf16*)(ws);                // over x_b
  bf16*  k_b   = (bf16*)(ws + 33554432);     // over wqkvt
  bf16*  v_t   = (bf16*)(ws + 35651584);     // over wqkvt tail
  bf16*  o_b   = (bf16*)(ws + 8388608);      // over qkv_f
  bf16*  wot   = (bf16*)(ws + 16777216);     // over qkv_f tail

  conv_x_kernel<<<2048, 256, 0, stream>>>(x, x_b);
  transpose_conv_kernel<<<dim3(16, 16), 256, 0, stream>>>(wq, wqkvt, CD, CNQ);
  transpose_conv_kernel<<<dim3(16, 4), 256, 0, stream>>>(wk, wqkvt + (size_t)1024 * CD, CD, CNKV);
  transpose_conv_kernel<<<dim3(16, 4), 256, 0, stream>>>(wv, wqkvt + (size_t)1280 * CD, CD, CNKV);
  gemm_mfma_kernel<<<dim3(32, 12), 256, 0, stream>>>(x_b, wqkvt, qkv_f, CM, 1536, CD, CD);
  rope_q_kernel<<<(CB * CS * CH * 32) / 256, 256, 0, stream>>>(qkv_f, fc, fs, q_b);
  rope_k_kernel<<<(CB * CS * CKH * 32) / 256, 256, 0, stream>>>(qkv_f, fc, fs, k_b);
  transpose_v_kernel<<<CB * CKH * 32, 256, 0, stream>>>(qkv_f, v_t);
  transpose_conv_kernel<<<dim3(16, 16), 256, 0, stream>>>(wo, wot, CNQ, CD);
  flash_mfma_kernel<<<256, 512, 0, stream>>>(q_b, k_b, v_t, o_b);
  gemm_mfma_kernel<<<dim3(32, 8), 256, 0, stream>>>(o_b, wot, out, CM, CD, CNQ, CNQ);
}

// Round 11
// 156.473 us; speedup vs baseline: 1.2476x; 1.2476x over previous
//
#include <hip/hip_runtime.h>
#include <hip/hip_bf16.h>

using bf16 = __hip_bfloat16;
typedef short bf16x8 __attribute__((ext_vector_type(8)));
typedef float f32x4 __attribute__((ext_vector_type(4)));

#define CB 2
#define CS 2048
#define CD 1024
#define CH 16
#define CKH 4
#define CHD 64
#define CREP 4
#define CNQ (CH*CHD)    // 1024
#define CNKV (CKH*CHD)  // 256
#define CM (CB*CS)      // 4096

__device__ __forceinline__ unsigned short f2bf(float f) {
  union { float f; unsigned int i; } c; c.f = f;
  unsigned int r = c.i + 0x7FFFu + ((c.i >> 16) & 1u);  // RNE
  return (unsigned short)(r >> 16);
}
__device__ __forceinline__ void gload_lds16(const void* g, void* l) {
  __builtin_amdgcn_global_load_lds(
      (const __attribute__((address_space(1))) void*)g,
      (__attribute__((address_space(3))) void*)l, 16, 0, 0);
}

// ---------------------------------------------------------------------------
// bf16 MFMA GEMM v2 (R8-proven): C[M,N] f32 = A[M,K](lda) · Bt[N,K]^T.
// 128x128, BK=32, dbuf LDS, counted vmcnt.
// ---------------------------------------------------------------------------
__global__ __launch_bounds__(256) void gemm_mfma_kernel(
    const bf16* __restrict__ A, const bf16* __restrict__ Bt,
    float* __restrict__ C, int Mm, int Nn, int Kk, int lda)
{
  __shared__ __align__(16) bf16 As[2][128 * 32];
  __shared__ __align__(16) bf16 Bs[2][128 * 32];
  const int tid = threadIdx.x;
  const int lane = tid & 63;
  const int l15 = lane & 15;
  const int g = lane >> 4;
  const int wid = tid >> 6;
  const int wr = (wid >> 1) * 64;
  const int wc = (wid & 1) * 64;
  const int m0 = blockIdx.x * 128;
  const int n0 = blockIdx.y * 128;

  f32x4 acc[4][4];
  #pragma unroll
  for (int i = 0; i < 4; ++i)
    #pragma unroll
    for (int j = 0; j < 4; ++j)
      acc[i][j] = (f32x4){0.f, 0.f, 0.f, 0.f};

  const int sr = tid >> 2;
  const int sc = (tid & 3) * 8;
  const bf16* aSrc = A + (size_t)(m0 + sr) * lda + sc;
  const bf16* bSrc = Bt + (size_t)(n0 + sr) * Kk + sc;
  const int sOff = (tid & 192) * 8;

#define GSTAGE(bi, k0) do {                                             \
    gload_lds16(aSrc + (k0),                     &As[bi][sOff]);        \
    gload_lds16(aSrc + 64 * (size_t)lda + (k0),  &As[bi][sOff + 2048]); \
    gload_lds16(bSrc + (k0),                     &Bs[bi][sOff]);        \
    gload_lds16(bSrc + 64 * (size_t)Kk + (k0),   &Bs[bi][sOff + 2048]); \
  } while (0)

  const int nt = Kk >> 5;
  int bi = 0;
  GSTAGE(0, 0);
  for (int t = 0; t < nt; ++t) {
    if (t + 1 < nt) {
      GSTAGE(bi ^ 1, (t + 1) * 32);
      asm volatile("s_waitcnt vmcnt(4)" ::: "memory");
    } else {
      asm volatile("s_waitcnt vmcnt(0)" ::: "memory");
    }
    __builtin_amdgcn_s_barrier();
    asm volatile("" ::: "memory");

    bf16x8 af[4], bfr[4];
    #pragma unroll
    for (int mt = 0; mt < 4; ++mt)
      af[mt] = *(const bf16x8*)&As[bi][(wr + mt * 16 + l15) * 32 + g * 8];
    #pragma unroll
    for (int nt2 = 0; nt2 < 4; ++nt2)
      bfr[nt2] = *(const bf16x8*)&Bs[bi][(wc + nt2 * 16 + l15) * 32 + g * 8];
    #pragma unroll
    for (int mt = 0; mt < 4; ++mt)
      #pragma unroll
      for (int nt2 = 0; nt2 < 4; ++nt2)
        acc[mt][nt2] = __builtin_amdgcn_mfma_f32_16x16x32_bf16(af[mt], bfr[nt2], acc[mt][nt2], 0, 0, 0);

    asm volatile("" ::: "memory");
    __builtin_amdgcn_s_barrier();
    bi ^= 1;
  }
#undef GSTAGE

  #pragma unroll
  for (int mt = 0; mt < 4; ++mt)
    #pragma unroll
    for (int r4 = 0; r4 < 4; ++r4) {
      const size_t row = (size_t)(m0 + wr + mt * 16 + 4 * g + r4);
      #pragma unroll
      for (int nt2 = 0; nt2 < 4; ++nt2)
        C[row * Nn + n0 + wc + nt2 * 16 + l15] = acc[mt][nt2][r4];
    }
}

// ---------------------------------------------------------------------------
__global__ void conv_x_kernel(const float* __restrict__ x, bf16* __restrict__ xb)
{
  int i = (blockIdx.x * 256 + threadIdx.x) * 8;
  float4 a = *(const float4*)&x[i];
  float4 b = *(const float4*)&x[i + 4];
  unsigned short* o = (unsigned short*)xb + i;
  *(ushort4*)o = make_ushort4(f2bf(a.x), f2bf(a.y), f2bf(a.z), f2bf(a.w));
  *(ushort4*)(o + 4) = make_ushort4(f2bf(b.x), f2bf(b.y), f2bf(b.z), f2bf(b.w));
}

// W[K][N] f32 -> Wt[N][K] bf16 (LDS-tiled 64x64 transpose + convert).
__global__ __launch_bounds__(256) void transpose_conv_kernel(
    const float* __restrict__ W, bf16* __restrict__ Wt, int Kk, int Nn)
{
  __shared__ float T[64][65];
  const int k0 = blockIdx.x * 64;
  const int n0 = blockIdx.y * 64;
  const int tid = threadIdx.x;
  const int lr = tid >> 4;
  const int lc = (tid & 15) * 4;
  #pragma unroll
  for (int i = 0; i < 4; ++i) {
    float4 v = *(const float4*)&W[(size_t)(k0 + lr + i * 16) * Nn + n0 + lc];
    T[lr + i * 16][lc + 0] = v.x;
    T[lr + i * 16][lc + 1] = v.y;
    T[lr + i * 16][lc + 2] = v.z;
    T[lr + i * 16][lc + 3] = v.w;
  }
  __syncthreads();
  const int rn = tid >> 3;
  const int ck = (tid & 7) * 8;
  #pragma unroll
  for (int i = 0; i < 2; ++i) {
    int nn = rn + i * 32;
    unsigned short u[8];
    #pragma unroll
    for (int e = 0; e < 8; ++e) u[e] = f2bf(T[ck + e][nn]);
    unsigned short* dst = (unsigned short*)Wt + (size_t)(n0 + nn) * Kk + k0 + ck;
    *(ushort4*)dst = make_ushort4(u[0], u[1], u[2], u[3]);
    *(ushort4*)(dst + 4) = make_ushort4(u[4], u[5], u[6], u[7]);
  }
}

// ---------------------------------------------------------------------------
// RoPE q from fused qkv buffer: qkv_f [B*S][1536], q at cols 0..1023.
__global__ void rope_q_kernel(const float* __restrict__ qf,
                              const float* __restrict__ fc,
                              const float* __restrict__ fs,
                              bf16* __restrict__ qb)
{
  int p = blockIdx.x * blockDim.x + threadIdx.x;
  int j = p & 31;
  int h = (p >> 5) & 15;
  int s = (p >> 9) & 2047;
  int b = p >> 20;
  const float* src = qf + (size_t)(b * CS + s) * 1536 + h * CHD + j * 2;
  float x0 = src[0], x1 = src[1];
  float c = fc[s * 32 + j], sn = fs[s * 32 + j];
  bf16* dst = qb + ((size_t)(b * CH + h) * CS + s) * CHD + j * 2;
  dst[0] = __float2bfloat16(x0 * c - x1 * sn);
  dst[1] = __float2bfloat16(x0 * sn + x1 * c);
}

// RoPE k from fused qkv buffer: k at cols 1024..1279.
__global__ void rope_k_kernel(const float* __restrict__ kvf,
                              const float* __restrict__ fc,
                              const float* __restrict__ fs,
                              bf16* __restrict__ kb)
{
  int p = blockIdx.x * blockDim.x + threadIdx.x;
  int j = p & 31;
  int kh = (p >> 5) & 3;
  int s = (p >> 7) & 2047;
  int b = p >> 18;
  const float* src = kvf + (size_t)(b * CS + s) * 1536 + 1024 + kh * CHD + j * 2;
  float x0 = src[0], x1 = src[1];
  float c = fc[s * 32 + j], sn = fs[s * 32 + j];
  bf16* dst = kb + ((size_t)(b * CKH + kh) * CS + s) * CHD + j * 2;
  dst[0] = __float2bfloat16(x0 * c - x1 * sn);
  dst[1] = __float2bfloat16(x0 * sn + x1 * c);
}

// V transpose: qkv_f [B*S][1536] (v at cols 1280..1535) -> vt [B,KH,HD,S] bf16.
__global__ __launch_bounds__(256) void transpose_v_kernel(
    const float* __restrict__ kvf, bf16* __restrict__ vt)
{
  __shared__ float T[64][65];
  const int blk = blockIdx.x;
  const int st = blk & 31;
  const int kh = (blk >> 5) & 3;
  const int b = blk >> 7;
  const int tid = threadIdx.x;
  const int s = tid >> 2;
  const int d0 = (tid & 3) * 16;
  const float* src = kvf + ((size_t)(b * CS + st * 64 + s)) * 1536 + 1280 + kh * CHD + d0;
  #pragma unroll
  for (int i = 0; i < 4; ++i) {
    float4 v = *(const float4*)(src + i * 4);
    T[s][d0 + i * 4 + 0] = v.x;
    T[s][d0 + i * 4 + 1] = v.y;
    T[s][d0 + i * 4 + 2] = v.z;
    T[s][d0 + i * 4 + 3] = v.w;
  }
  __syncthreads();
  const int d = tid >> 2;
  const int s0 = (tid & 3) * 16;
  unsigned short* dst = (unsigned short*)vt +
      ((size_t)((b * CKH + kh) * CHD + d)) * CS + st * 64 + s0;
  #pragma unroll
  for (int i = 0; i < 2; ++i) {
    unsigned short u[8];
    #pragma unroll
    for (int e = 0; e < 8; ++e) u[e] = f2bf(T[s0 + i * 8 + e][d]);
    *(ushort4*)(dst + i * 8 + 0) = make_ushort4(u[0], u[1], u[2], u[3]);
    *(ushort4*)(dst + i * 8 + 4) = make_ushort4(u[4], u[5], u[6], u[7]);
  }
}

// ---------------------------------------------------------------------------
// MFMA flash attention v7c: R10 structure (8 waves = 4 heads x 2 consecutive
// q-tiles sharing the K/V LDS stream, natural launch bounds) with the PROVEN
// f2bf scalar P-pack instead of hand-written v_cvt_pk_bf16_f32 inline asm
// (single-variable bisection: cvt_pk asm present in both NaN failures R7/R10,
// absent in all clean passes).
// ---------------------------------------------------------------------------
__global__ __launch_bounds__(512) void flash_mfma_kernel(
    const bf16* __restrict__ qb, const bf16* __restrict__ kb,
    const bf16* __restrict__ vt, bf16* __restrict__ ob)
{
  __shared__ __align__(16) char arena[69632];
  char* KL = arena;                       // [2][8192]: K tile 64x(64 bf16)
  char* VL = arena + 16384;               // [2][8192]: V^T tile 64x(64 bf16)
  const int tid = threadIdx.x;            // 0..511
  const int lane = tid & 63;
  const int wid = tid >> 6;               // 0..7
  unsigned short* PLW = (unsigned short*)(arena + 32768) + wid * 2304; // [32][72]
  const int l15 = lane & 15;
  const int g = lane >> 4;
  const int blk = blockIdx.x;
  const int grp = blk & 7;                // b*4+kh (XCD spread)
  const int jp = 31 - (blk >> 3);         // LPT: longest pair first
  const int kh = grp & 3;
  const int b = grp >> 2;
  const int hw = wid & 3;                 // head within kv group
  const int qh = wid >> 2;                // which q-tile of the pair
  const int h = kh * CREP + hw;
  const int qt = 2 * jp + qh;
  const int N64 = jp + 1;                 // 64-key tiles (diag in tile jp)
  const float SC = 0.18033688f;           // 0.125 * log2(e)

  const bf16* qbase = qb + ((size_t)(b * CH + h) * CS + qt * 32) * CHD;
  const bf16* kbase = kb + (size_t)(b * CKH + kh) * CS * CHD;
  const bf16* vbase = vt + (size_t)(b * CKH + kh) * CHD * CS;  // [d][s]

  bf16x8 qf[2][2];
  #pragma unroll
  for (int qs = 0; qs < 2; ++qs)
    #pragma unroll
    for (int c = 0; c < 2; ++c)
      qf[qs][c] = *(const bf16x8*)(qbase + (qs * 16 + l15) * CHD + c * 32 + g * 8);

  bf16x8 ones;
  #pragma unroll
  for (int e = 0; e < 8; ++e) ones[e] = (short)0x3F80;  // bf16 1.0

  f32x4 oacc[2][4];
  f32x4 lacc[2];
  #pragma unroll
  for (int qs = 0; qs < 2; ++qs) {
    lacc[qs] = (f32x4){0.f, 0.f, 0.f, 0.f};
    #pragma unroll
    for (int dt = 0; dt < 4; ++dt)
      oacc[qs][dt] = (f32x4){0.f, 0.f, 0.f, 0.f};
  }
  float mrow[2] = {-1e30f, -1e30f};

  // staging: 512 threads x 16B = one full 8KB tile per gload.
  // thread t -> row t>>3, LDS chunk t&7 holds global chunk (t&7)^(row&7).
  const int slr = tid >> 3;               // 0..63
  const int scg = (tid & 7) ^ (slr & 7);
  const bf16* kstage = kbase + (size_t)slr * CHD + scg * 8;
  const bf16* vstage = vbase + (size_t)slr * CS + scg * 8;
  char* kdst = KL + wid * 1024;           // wave-uniform base (+lane*16 by HW)
  char* vdst = VL + wid * 1024;

#define STAGE(bi, t64) do {                                             \
    gload_lds16(kstage + (size_t)(t64) * 64 * CHD, kdst + (bi) * 8192); \
    gload_lds16(vstage + (t64) * 64,               vdst + (bi) * 8192); \
  } while (0)

  int bi = 0;
  STAGE(0, 0);
  for (int t = 0; t < N64; ++t) {
    if (t + 1 < N64) {
      STAGE(bi ^ 1, t + 1);
      asm volatile("s_waitcnt vmcnt(2)" ::: "memory");  // tile-t loads done
    } else {
      asm volatile("s_waitcnt vmcnt(0)" ::: "memory");
    }
    __builtin_amdgcn_s_barrier();
    asm volatile("" ::: "memory");

    const char* KB = KL + bi * 8192;
    const char* VB = VL + bi * 8192;
    bf16x8 kfr[4][2], vfr[4][2];
    #pragma unroll
    for (int kt = 0; kt < 4; ++kt) {
      int row = kt * 16 + l15;
      #pragma unroll
      for (int c = 0; c < 2; ++c)
        kfr[kt][c] = *(const bf16x8*)(KB + row * 128 + (((c * 4 + g) ^ (row & 7)) << 4));
    }
    #pragma unroll
    for (int dt = 0; dt < 4; ++dt) {
      int row = dt * 16 + l15;
      #pragma unroll
      for (int st = 0; st < 2; ++st)
        vfr[dt][st] = *(const bf16x8*)(VB + row * 128 + (((st * 4 + g) ^ (row & 7)) << 4));
    }

    // QK^T (swapped): S^T[k][q]
    f32x4 sacc[4][2];
    #pragma unroll
    for (int kt = 0; kt < 4; ++kt)
      #pragma unroll
      for (int qs = 0; qs < 2; ++qs)
        sacc[kt][qs] = (f32x4){0.f, 0.f, 0.f, 0.f};
    #pragma unroll
    for (int c = 0; c < 2; ++c)
      #pragma unroll
      for (int kt = 0; kt < 4; ++kt)
        #pragma unroll
        for (int qs = 0; qs < 2; ++qs)
          sacc[kt][qs] = __builtin_amdgcn_mfma_f32_16x16x32_bf16(kfr[kt][c], qf[qs][c], sacc[kt][qs], 0, 0, 0);

    const bool diag = (t == N64 - 1);
    #pragma unroll
    for (int qs = 0; qs < 2; ++qs) {
      float e[16];
      float pm = -1e30f;
      #pragma unroll
      for (int kt = 0; kt < 4; ++kt)
        #pragma unroll
        for (int r = 0; r < 4; ++r) {
          float v = sacc[kt][qs][r] * SC;
          if (diag) {
            int koff = kt * 16 + 4 * g + r;           // local key in tile jp
            if (koff > qh * 32 + qs * 16 + l15) v = -1e30f;
          }
          e[kt * 4 + r] = v;
          pm = fmaxf(pm, v);
        }
      if (__any(pm > mrow[qs] + 8.0f)) {       // slow path: exact rescale
        pm = fmaxf(pm, __shfl_xor(pm, 16, 64));
        pm = fmaxf(pm, __shfl_xor(pm, 32, 64));
        float nm = fmaxf(mrow[qs], pm);
        float corr = exp2f(mrow[qs] - nm);
        mrow[qs] = nm;
        lacc[qs] *= corr;
        #pragma unroll
        for (int dt = 0; dt < 4; ++dt) oacc[qs][dt] *= corr;
      }
      unsigned short pb[16];
      #pragma unroll
      for (int i = 0; i < 16; ++i)
        pb[i] = f2bf(exp2f(e[i] - mrow[qs]));  // p <= 2^8
      #pragma unroll
      for (int kt = 0; kt < 4; ++kt)
        *(ushort4*)&PLW[(qs * 16 + l15) * 72 + kt * 16 + 4 * g] =
            make_ushort4(pb[kt * 4 + 0], pb[kt * 4 + 1], pb[kt * 4 + 2], pb[kt * 4 + 3]);
    }

    // PV + psum (same-wave LDS RAW)
    #pragma unroll
    for (int qs = 0; qs < 2; ++qs) {
      #pragma unroll
      for (int st = 0; st < 2; ++st) {
        bf16x8 pf = *(const bf16x8*)&PLW[(qs * 16 + l15) * 72 + st * 32 + g * 8];
        lacc[qs] = __builtin_amdgcn_mfma_f32_16x16x32_bf16(ones, pf, lacc[qs], 0, 0, 0);
        #pragma unroll
        for (int dt = 0; dt < 4; ++dt)
          oacc[qs][dt] = __builtin_amdgcn_mfma_f32_16x16x32_bf16(vfr[dt][st], pf, oacc[qs][dt], 0, 0, 0);
      }
    }

    asm volatile("" ::: "memory");
    __builtin_amdgcn_s_barrier();            // all reads of buf bi done
    bi ^= 1;
  }
#undef STAGE

  #pragma unroll
  for (int qs = 0; qs < 2; ++qs) {
    float inv = 1.0f / lacc[qs][0];
    int qg = qt * 32 + qs * 16 + l15;
    unsigned short* orow = (unsigned short*)ob + (size_t)(b * CS + qg) * CNQ + h * CHD;
    #pragma unroll
    for (int dt = 0; dt < 4; ++dt) {
      *(ushort4*)&orow[dt * 16 + 4 * g] =
          make_ushort4(f2bf(oacc[qs][dt][0] * inv), f2bf(oacc[qs][dt][1] * inv),
                       f2bf(oacc[qs][dt][2] * inv), f2bf(oacc[qs][dt][3] * inv));
    }
  }
}

// ---------------------------------------------------------------------------
extern "C" void kernel_launch(void* const* d_in, const int* in_sizes, int n_in,
                              void* d_out, int out_size, void* d_ws, size_t ws_size,
                              hipStream_t stream)
{
  const float* x  = (const float*)d_in[0];
  const float* wq = (const float*)d_in[1];
  const float* wk = (const float*)d_in[2];
  const float* wv = (const float*)d_in[3];
  const float* wo = (const float*)d_in[4];
  const float* fc = (const float*)d_in[5];
  const float* fs = (const float*)d_in[6];
  float* out = (float*)d_out;

  char* ws = (char*)d_ws;
  // workspace (peak 37.75MB, R8-proven layout):
  bf16*  x_b   = (bf16*)(ws);                // [0,8M)  dead after qkv GEMM
  float* qkv_f = (float*)(ws + 8388608);     // [8M,33.5M)
  bf16*  wqkvt = (bf16*)(ws + 33554432);     // [33.5M,36.7M) dead after GEMM
  bf16*  q_b   = (bf16*)(ws);                // over x_b
  bf16*  k_b   = (bf16*)(ws + 33554432);     // over wqkvt
  bf16*  v_t   = (bf16*)(ws + 35651584);     // over wqkvt tail
  bf16*  o_b   = (bf16*)(ws + 8388608);      // over qkv_f
  bf16*  wot   = (bf16*)(ws + 16777216);     // over qkv_f tail

  conv_x_kernel<<<2048, 256, 0, stream>>>(x, x_b);
  transpose_conv_kernel<<<dim3(16, 16), 256, 0, stream>>>(wq, wqkvt, CD, CNQ);
  transpose_conv_kernel<<<dim3(16, 4), 256, 0, stream>>>(wk, wqkvt + (size_t)1024 * CD, CD, CNKV);
  transpose_conv_kernel<<<dim3(16, 4), 256, 0, stream>>>(wv, wqkvt + (size_t)1280 * CD, CD, CNKV);
  gemm_mfma_kernel<<<dim3(32, 12), 256, 0, stream>>>(x_b, wqkvt, qkv_f, CM, 1536, CD, CD);
  rope_q_kernel<<<(CB * CS * CH * 32) / 256, 256, 0, stream>>>(qkv_f, fc, fs, q_b);
  rope_k_kernel<<<(CB * CS * CKH * 32) / 256, 256, 0, stream>>>(qkv_f, fc, fs, k_b);
  transpose_v_kernel<<<CB * CKH * 32, 256, 0, stream>>>(qkv_f, v_t);
  transpose_conv_kernel<<<dim3(16, 16), 256, 0, stream>>>(wo, wot, CNQ, CD);
  flash_mfma_kernel<<<256, 512, 0, stream>>>(q_b, k_b, v_t, o_b);
  gemm_mfma_kernel<<<dim3(32, 8), 256, 0, stream>>>(o_b, wot, out, CM, CD, CNQ, CNQ);
}

// Round 12
// 135.205 us; speedup vs baseline: 1.4438x; 1.1573x over previous
//
#include <hip/hip_runtime.h>
#include <hip/hip_bf16.h>

using bf16 = __hip_bfloat16;
typedef short bf16x8 __attribute__((ext_vector_type(8)));
typedef float f32x4 __attribute__((ext_vector_type(4)));

#define CB 2
#define CS 2048
#define CD 1024
#define CH 16
#define CKH 4
#define CHD 64
#define CREP 4
#define CNQ (CH*CHD)    // 1024
#define CNKV (CKH*CHD)  // 256
#define CM (CB*CS)      // 4096

__device__ __forceinline__ unsigned short f2bf(float f) {
  union { float f; unsigned int i; } c; c.f = f;
  unsigned int r = c.i + 0x7FFFu + ((c.i >> 16) & 1u);  // RNE
  return (unsigned short)(r >> 16);
}
__device__ __forceinline__ void gload_lds16(const void* g, void* l) {
  __builtin_amdgcn_global_load_lds(
      (const __attribute__((address_space(1))) void*)g,
      (__attribute__((address_space(3))) void*)l, 16, 0, 0);
}

// ---------------------------------------------------------------------------
// bf16 MFMA GEMM v2 (R8-proven): C[M,N] f32 = A[M,K](lda) · Bt[N,K]^T.
// 128x128, BK=32, dbuf LDS, counted vmcnt. Used for the o-projection.
// ---------------------------------------------------------------------------
__global__ __launch_bounds__(256) void gemm_mfma_kernel(
    const bf16* __restrict__ A, const bf16* __restrict__ Bt,
    float* __restrict__ C, int Mm, int Nn, int Kk, int lda)
{
  __shared__ __align__(16) bf16 As[2][128 * 32];
  __shared__ __align__(16) bf16 Bs[2][128 * 32];
  const int tid = threadIdx.x;
  const int lane = tid & 63;
  const int l15 = lane & 15;
  const int g = lane >> 4;
  const int wid = tid >> 6;
  const int wr = (wid >> 1) * 64;
  const int wc = (wid & 1) * 64;
  const int m0 = blockIdx.x * 128;
  const int n0 = blockIdx.y * 128;

  f32x4 acc[4][4];
  #pragma unroll
  for (int i = 0; i < 4; ++i)
    #pragma unroll
    for (int j = 0; j < 4; ++j)
      acc[i][j] = (f32x4){0.f, 0.f, 0.f, 0.f};

  const int sr = tid >> 2;
  const int sc = (tid & 3) * 8;
  const bf16* aSrc = A + (size_t)(m0 + sr) * lda + sc;
  const bf16* bSrc = Bt + (size_t)(n0 + sr) * Kk + sc;
  const int sOff = (tid & 192) * 8;

#define GSTAGE(bi, k0) do {                                             \
    gload_lds16(aSrc + (k0),                     &As[bi][sOff]);        \
    gload_lds16(aSrc + 64 * (size_t)lda + (k0),  &As[bi][sOff + 2048]); \
    gload_lds16(bSrc + (k0),                     &Bs[bi][sOff]);        \
    gload_lds16(bSrc + 64 * (size_t)Kk + (k0),   &Bs[bi][sOff + 2048]); \
  } while (0)

  const int nt = Kk >> 5;
  int bi = 0;
  GSTAGE(0, 0);
  for (int t = 0; t < nt; ++t) {
    if (t + 1 < nt) {
      GSTAGE(bi ^ 1, (t + 1) * 32);
      asm volatile("s_waitcnt vmcnt(4)" ::: "memory");
    } else {
      asm volatile("s_waitcnt vmcnt(0)" ::: "memory");
    }
    __builtin_amdgcn_s_barrier();
    asm volatile("" ::: "memory");

    bf16x8 af[4], bfr[4];
    #pragma unroll
    for (int mt = 0; mt < 4; ++mt)
      af[mt] = *(const bf16x8*)&As[bi][(wr + mt * 16 + l15) * 32 + g * 8];
    #pragma unroll
    for (int nt2 = 0; nt2 < 4; ++nt2)
      bfr[nt2] = *(const bf16x8*)&Bs[bi][(wc + nt2 * 16 + l15) * 32 + g * 8];
    #pragma unroll
    for (int mt = 0; mt < 4; ++mt)
      #pragma unroll
      for (int nt2 = 0; nt2 < 4; ++nt2)
        acc[mt][nt2] = __builtin_amdgcn_mfma_f32_16x16x32_bf16(af[mt], bfr[nt2], acc[mt][nt2], 0, 0, 0);

    asm volatile("" ::: "memory");
    __builtin_amdgcn_s_barrier();
    bi ^= 1;
  }
#undef GSTAGE

  #pragma unroll
  for (int mt = 0; mt < 4; ++mt)
    #pragma unroll
    for (int r4 = 0; r4 < 4; ++r4) {
      const size_t row = (size_t)(m0 + wr + mt * 16 + 4 * g + r4);
      #pragma unroll
      for (int nt2 = 0; nt2 < 4; ++nt2)
        C[row * Nn + n0 + wc + nt2 * 16 + l15] = acc[mt][nt2][r4];
    }
}

// ---------------------------------------------------------------------------
// qkv GEMM with fused RoPE + layout epilogue. Same 128x128 dbuf body.
// N=1536 (q:0..1023, k:1024..1279, v:1280..1535); blockIdx.y picks region
// (0..7=q, 8..9=k, 10..11=v) -> wave-uniform epilogue branch.
// q: rope, write bf16 [B,H,S,HD]. k: rope, write bf16 [B,KH,S,HD].
// v: write bf16 V^T [B,KH,HD,S] (4 consecutive-s acc regs = one 8B store).
// Rotation pairs = adjacent columns = adjacent lanes: partner via shfl_xor(1),
// out = val*c -/+ partner*sn (even/odd d).
// ---------------------------------------------------------------------------
__global__ __launch_bounds__(256) void gemm_qkv_rope_kernel(
    const bf16* __restrict__ A, const bf16* __restrict__ Bt,
    const float* __restrict__ fc, const float* __restrict__ fs,
    bf16* __restrict__ qb, bf16* __restrict__ kb, bf16* __restrict__ vt)
{
  __shared__ __align__(16) bf16 As[2][128 * 32];
  __shared__ __align__(16) bf16 Bs[2][128 * 32];
  const int tid = threadIdx.x;
  const int lane = tid & 63;
  const int l15 = lane & 15;
  const int g = lane >> 4;
  const int wid = tid >> 6;
  const int wr = (wid >> 1) * 64;
  const int wc = (wid & 1) * 64;
  const int m0 = blockIdx.x * 128;
  const int n0 = blockIdx.y * 128;
  const int Kk = CD;

  f32x4 acc[4][4];
  #pragma unroll
  for (int i = 0; i < 4; ++i)
    #pragma unroll
    for (int j = 0; j < 4; ++j)
      acc[i][j] = (f32x4){0.f, 0.f, 0.f, 0.f};

  const int sr = tid >> 2;
  const int sc = (tid & 3) * 8;
  const bf16* aSrc = A + (size_t)(m0 + sr) * Kk + sc;
  const bf16* bSrc = Bt + (size_t)(n0 + sr) * Kk + sc;
  const int sOff = (tid & 192) * 8;

#define GSTAGE(bi, k0) do {                                             \
    gload_lds16(aSrc + (k0),                     &As[bi][sOff]);        \
    gload_lds16(aSrc + 64 * (size_t)Kk + (k0),   &As[bi][sOff + 2048]); \
    gload_lds16(bSrc + (k0),                     &Bs[bi][sOff]);        \
    gload_lds16(bSrc + 64 * (size_t)Kk + (k0),   &Bs[bi][sOff + 2048]); \
  } while (0)

  const int nt = Kk >> 5;
  int bi = 0;
  GSTAGE(0, 0);
  for (int t = 0; t < nt; ++t) {
    if (t + 1 < nt) {
      GSTAGE(bi ^ 1, (t + 1) * 32);
      asm volatile("s_waitcnt vmcnt(4)" ::: "memory");
    } else {
      asm volatile("s_waitcnt vmcnt(0)" ::: "memory");
    }
    __builtin_amdgcn_s_barrier();
    asm volatile("" ::: "memory");

    bf16x8 af[4], bfr[4];
    #pragma unroll
    for (int mt = 0; mt < 4; ++mt)
      af[mt] = *(const bf16x8*)&As[bi][(wr + mt * 16 + l15) * 32 + g * 8];
    #pragma unroll
    for (int nt2 = 0; nt2 < 4; ++nt2)
      bfr[nt2] = *(const bf16x8*)&Bs[bi][(wc + nt2 * 16 + l15) * 32 + g * 8];
    #pragma unroll
    for (int mt = 0; mt < 4; ++mt)
      #pragma unroll
      for (int nt2 = 0; nt2 < 4; ++nt2)
        acc[mt][nt2] = __builtin_amdgcn_mfma_f32_16x16x32_bf16(af[mt], bfr[nt2], acc[mt][nt2], 0, 0, 0);

    asm volatile("" ::: "memory");
    __builtin_amdgcn_s_barrier();
    bi ^= 1;
  }
#undef GSTAGE

  if (blockIdx.y < 10) {
    // q or k region: RoPE then scatter bf16
    const bool isq = (blockIdx.y < 8);
    #pragma unroll
    for (int mt = 0; mt < 4; ++mt)
      #pragma unroll
      for (int r4 = 0; r4 < 4; ++r4) {
        int m = m0 + wr + mt * 16 + 4 * g + r4;
        int s = m & (CS - 1), bb = m >> 11;
        #pragma unroll
        for (int nt2 = 0; nt2 < 4; ++nt2) {
          int n = n0 + wc + nt2 * 16 + l15;
          int d = n & 63;
          float val = acc[mt][nt2][r4];
          float par = __shfl_xor(val, 1, 64);
          float cv = fc[s * 32 + (d >> 1)];
          float sv = fs[s * 32 + (d >> 1)];
          float o = (d & 1) ? (par * sv + val * cv) : (val * cv - par * sv);
          if (isq) {
            int h = n >> 6;
            ((unsigned short*)qb)[(((size_t)bb * CH + h) * CS + s) * CHD + d] = f2bf(o);
          } else {
            int kh = (n >> 6) - 16;
            ((unsigned short*)kb)[(((size_t)bb * CKH + kh) * CS + s) * CHD + d] = f2bf(o);
          }
        }
      }
  } else {
    // v region: transpose write, 4 consecutive s per 8B store
    #pragma unroll
    for (int mt = 0; mt < 4; ++mt) {
      int mb = m0 + wr + mt * 16 + 4 * g;
      int s0 = mb & (CS - 1), bb = mb >> 11;
      #pragma unroll
      for (int nt2 = 0; nt2 < 4; ++nt2) {
        int n = n0 + wc + nt2 * 16 + l15;
        int d = n & 63;
        int kh = (n >> 6) - 20;
        ushort4 pk = make_ushort4(f2bf(acc[mt][nt2][0]), f2bf(acc[mt][nt2][1]),
                                  f2bf(acc[mt][nt2][2]), f2bf(acc[mt][nt2][3]));
        *(ushort4*)&((unsigned short*)vt)[(((size_t)bb * CKH + kh) * CHD + d) * CS + s0] = pk;
      }
    }
  }
}

// ---------------------------------------------------------------------------
__global__ void conv_x_kernel(const float* __restrict__ x, bf16* __restrict__ xb)
{
  int i = (blockIdx.x * 256 + threadIdx.x) * 8;
  float4 a = *(const float4*)&x[i];
  float4 b = *(const float4*)&x[i + 4];
  unsigned short* o = (unsigned short*)xb + i;
  *(ushort4*)o = make_ushort4(f2bf(a.x), f2bf(a.y), f2bf(a.z), f2bf(a.w));
  *(ushort4*)(o + 4) = make_ushort4(f2bf(b.x), f2bf(b.y), f2bf(b.z), f2bf(b.w));
}

// W[K][N] f32 -> Wt[N][K] bf16 (LDS-tiled 64x64 transpose + convert).
__global__ __launch_bounds__(256) void transpose_conv_kernel(
    const float* __restrict__ W, bf16* __restrict__ Wt, int Kk, int Nn)
{
  __shared__ float T[64][65];
  const int k0 = blockIdx.x * 64;
  const int n0 = blockIdx.y * 64;
  const int tid = threadIdx.x;
  const int lr = tid >> 4;
  const int lc = (tid & 15) * 4;
  #pragma unroll
  for (int i = 0; i < 4; ++i) {
    float4 v = *(const float4*)&W[(size_t)(k0 + lr + i * 16) * Nn + n0 + lc];
    T[lr + i * 16][lc + 0] = v.x;
    T[lr + i * 16][lc + 1] = v.y;
    T[lr + i * 16][lc + 2] = v.z;
    T[lr + i * 16][lc + 3] = v.w;
  }
  __syncthreads();
  const int rn = tid >> 3;
  const int ck = (tid & 7) * 8;
  #pragma unroll
  for (int i = 0; i < 2; ++i) {
    int nn = rn + i * 32;
    unsigned short u[8];
    #pragma unroll
    for (int e = 0; e < 8; ++e) u[e] = f2bf(T[ck + e][nn]);
    unsigned short* dst = (unsigned short*)Wt + (size_t)(n0 + nn) * Kk + k0 + ck;
    *(ushort4*)dst = make_ushort4(u[0], u[1], u[2], u[3]);
    *(ushort4*)(dst + 4) = make_ushort4(u[4], u[5], u[6], u[7]);
  }
}

// ---------------------------------------------------------------------------
// MFMA flash attention: EXACT R8 kernel (proven 59.8us). 4 waves = 4 q-heads,
// one 32-row q-tile, KVBLK=64, dbuf LDS staging, counted vmcnt, XOR swizzle,
// defer-max softmax, psum-via-MFMA, f2bf P-pack.
// ---------------------------------------------------------------------------
__global__ __launch_bounds__(256, 2) void flash_mfma_kernel(
    const bf16* __restrict__ qb, const bf16* __restrict__ kb,
    const bf16* __restrict__ vt, bf16* __restrict__ ob)
{
  __shared__ __align__(16) char arena[51200];
  char* KL = arena;                       // [2][8192]: K tile 64x(64 bf16)
  char* VL = arena + 16384;               // [2][8192]: V^T tile 64x(64 bf16)
  const int tid = threadIdx.x;
  const int lane = tid & 63;
  const int wid = tid >> 6;
  unsigned short* PLW = (unsigned short*)(arena + 32768) + wid * 2304; // [32][72]
  const int l15 = lane & 15;
  const int g = lane >> 4;
  const int blk = blockIdx.x;
  const int grp = blk & 7;                // b*4+kh
  const int qt = 63 - (blk >> 3);         // LPT
  const int kh = grp & 3;
  const int b = grp >> 2;
  const int h = kh * CREP + wid;
  const int N64 = (qt >> 1) + 1;
  const float SC = 0.18033688f;           // 0.125 * log2(e)

  const bf16* qbase = qb + ((size_t)(b * CH + h) * CS + qt * 32) * CHD;
  const bf16* kbase = kb + (size_t)(b * CKH + kh) * CS * CHD;
  const bf16* vbase = vt + (size_t)(b * CKH + kh) * CHD * CS;  // [d][s]

  bf16x8 qf[2][2];
  #pragma unroll
  for (int qs = 0; qs < 2; ++qs)
    #pragma unroll
    for (int c = 0; c < 2; ++c)
      qf[qs][c] = *(const bf16x8*)(qbase + (qs * 16 + l15) * CHD + c * 32 + g * 8);

  bf16x8 ones;
  #pragma unroll
  for (int e = 0; e < 8; ++e) ones[e] = (short)0x3F80;  // bf16 1.0

  f32x4 oacc[2][4];
  f32x4 lacc[2];
  #pragma unroll
  for (int qs = 0; qs < 2; ++qs) {
    lacc[qs] = (f32x4){0.f, 0.f, 0.f, 0.f};
    #pragma unroll
    for (int dt = 0; dt < 4; ++dt)
      oacc[qs][dt] = (f32x4){0.f, 0.f, 0.f, 0.f};
  }
  float mrow[2] = {-1e30f, -1e30f};

  const int slr = tid >> 3;
  const int scg = (tid & 7) ^ (slr & 7);
  const bf16* kstage = kbase + (size_t)slr * CHD + scg * 8;
  const bf16* vstage = vbase + (size_t)slr * CS + scg * 8;
  char* kdst = KL + wid * 1024;
  char* vdst = VL + wid * 1024;

#define STAGE(bi, t64) do {                                        \
    const bf16* ks_ = kstage + (size_t)(t64) * 64 * CHD;           \
    const bf16* vs_ = vstage + (t64) * 64;                         \
    gload_lds16(ks_,            kdst + (bi) * 8192);               \
    gload_lds16(ks_ + 32 * CHD, kdst + (bi) * 8192 + 4096);        \
    gload_lds16(vs_,            vdst + (bi) * 8192);               \
    gload_lds16(vs_ + 32 * CS,  vdst + (bi) * 8192 + 4096);        \
  } while (0)

  int bi = 0;
  STAGE(0, 0);
  for (int t = 0; t < N64; ++t) {
    if (t + 1 < N64) {
      STAGE(bi ^ 1, t + 1);
      asm volatile("s_waitcnt vmcnt(4)" ::: "memory");
    } else {
      asm volatile("s_waitcnt vmcnt(0)" ::: "memory");
    }
    __builtin_amdgcn_s_barrier();
    asm volatile("" ::: "memory");

    const char* KB = KL + bi * 8192;
    const char* VB = VL + bi * 8192;
    bf16x8 kfr[4][2], vfr[4][2];
    #pragma unroll
    for (int kt = 0; kt < 4; ++kt) {
      int row = kt * 16 + l15;
      #pragma unroll
      for (int c = 0; c < 2; ++c)
        kfr[kt][c] = *(const bf16x8*)(KB + row * 128 + (((c * 4 + g) ^ (row & 7)) << 4));
    }
    #pragma unroll
    for (int dt = 0; dt < 4; ++dt) {
      int row = dt * 16 + l15;
      #pragma unroll
      for (int st = 0; st < 2; ++st)
        vfr[dt][st] = *(const bf16x8*)(VB + row * 128 + (((st * 4 + g) ^ (row & 7)) << 4));
    }

    // QK^T (swapped): S^T[k][q]
    f32x4 sacc[4][2];
    #pragma unroll
    for (int kt = 0; kt < 4; ++kt)
      #pragma unroll
      for (int qs = 0; qs < 2; ++qs)
        sacc[kt][qs] = (f32x4){0.f, 0.f, 0.f, 0.f};
    #pragma unroll
    for (int c = 0; c < 2; ++c)
      #pragma unroll
      for (int kt = 0; kt < 4; ++kt)
        #pragma unroll
        for (int qs = 0; qs < 2; ++qs)
          sacc[kt][qs] = __builtin_amdgcn_mfma_f32_16x16x32_bf16(kfr[kt][c], qf[qs][c], sacc[kt][qs], 0, 0, 0);

    const bool diag = (t == N64 - 1);
    #pragma unroll
    for (int qs = 0; qs < 2; ++qs) {
      float e[16];
      float pm = -1e30f;
      #pragma unroll
      for (int kt = 0; kt < 4; ++kt)
        #pragma unroll
        for (int r = 0; r < 4; ++r) {
          float v = sacc[kt][qs][r] * SC;
          if (diag) {
            int koff = t * 64 + kt * 16 + 4 * g + r;
            if (koff > qt * 32 + qs * 16 + l15) v = -1e30f;
          }
          e[kt * 4 + r] = v;
          pm = fmaxf(pm, v);
        }
      if (__any(pm > mrow[qs] + 8.0f)) {       // slow path: exact rescale
        pm = fmaxf(pm, __shfl_xor(pm, 16, 64));
        pm = fmaxf(pm, __shfl_xor(pm, 32, 64));
        float nm = fmaxf(mrow[qs], pm);
        float corr = exp2f(mrow[qs] - nm);
        mrow[qs] = nm;
        lacc[qs] *= corr;
        #pragma unroll
        for (int dt = 0; dt < 4; ++dt) oacc[qs][dt] *= corr;
      }
      unsigned short pb[16];
      #pragma unroll
      for (int i = 0; i < 16; ++i)
        pb[i] = f2bf(exp2f(e[i] - mrow[qs]));  // p <= 2^8
      #pragma unroll
      for (int kt = 0; kt < 4; ++kt)
        *(ushort4*)&PLW[(qs * 16 + l15) * 72 + kt * 16 + 4 * g] =
            make_ushort4(pb[kt * 4 + 0], pb[kt * 4 + 1], pb[kt * 4 + 2], pb[kt * 4 + 3]);
    }

    // PV + psum (same-wave LDS RAW)
    #pragma unroll
    for (int qs = 0; qs < 2; ++qs) {
      #pragma unroll
      for (int st = 0; st < 2; ++st) {
        bf16x8 pf = *(const bf16x8*)&PLW[(qs * 16 + l15) * 72 + st * 32 + g * 8];
        lacc[qs] = __builtin_amdgcn_mfma_f32_16x16x32_bf16(ones, pf, lacc[qs], 0, 0, 0);
        #pragma unroll
        for (int dt = 0; dt < 4; ++dt)
          oacc[qs][dt] = __builtin_amdgcn_mfma_f32_16x16x32_bf16(vfr[dt][st], pf, oacc[qs][dt], 0, 0, 0);
      }
    }

    asm volatile("" ::: "memory");
    __builtin_amdgcn_s_barrier();
    bi ^= 1;
  }
#undef STAGE

  #pragma unroll
  for (int qs = 0; qs < 2; ++qs) {
    float inv = 1.0f / lacc[qs][0];
    int qg = qt * 32 + qs * 16 + l15;
    unsigned short* orow = (unsigned short*)ob + (size_t)(b * CS + qg) * CNQ + h * CHD;
    #pragma unroll
    for (int dt = 0; dt < 4; ++dt) {
      *(ushort4*)&orow[dt * 16 + 4 * g] =
          make_ushort4(f2bf(oacc[qs][dt][0] * inv), f2bf(oacc[qs][dt][1] * inv),
                       f2bf(oacc[qs][dt][2] * inv), f2bf(oacc[qs][dt][3] * inv));
    }
  }
}

// ---------------------------------------------------------------------------
extern "C" void kernel_launch(void* const* d_in, const int* in_sizes, int n_in,
                              void* d_out, int out_size, void* d_ws, size_t ws_size,
                              hipStream_t stream)
{
  const float* x  = (const float*)d_in[0];
  const float* wq = (const float*)d_in[1];
  const float* wk = (const float*)d_in[2];
  const float* wv = (const float*)d_in[3];
  const float* wo = (const float*)d_in[4];
  const float* fc = (const float*)d_in[5];
  const float* fs = (const float*)d_in[6];
  float* out = (float*)d_out;

  char* ws = (char*)d_ws;
  // workspace (peak 34.6MB, no aliasing):
  bf16*  x_b   = (bf16*)(ws);                 // [0, 8M)
  bf16*  wqkvt = (bf16*)(ws + 8388608);       // [8M, 11M)   1536x1024 bf16
  bf16*  wot   = (bf16*)(ws + 11534336);      // [11M, 13M)  1024x1024 bf16
  bf16*  q_b   = (bf16*)(ws + 13631488);      // [13M, 21M)  [B,H,S,HD]
  bf16*  k_b   = (bf16*)(ws + 22020096);      // [21M, 23M)  [B,KH,S,HD]
  bf16*  v_t   = (bf16*)(ws + 24117248);      // [23M, 25M)  [B,KH,HD,S]
  bf16*  o_b   = (bf16*)(ws + 26214400);      // [25M, 33M)

  conv_x_kernel<<<2048, 256, 0, stream>>>(x, x_b);
  transpose_conv_kernel<<<dim3(16, 16), 256, 0, stream>>>(wq, wqkvt, CD, CNQ);
  transpose_conv_kernel<<<dim3(16, 4), 256, 0, stream>>>(wk, wqkvt + (size_t)1024 * CD, CD, CNKV);
  transpose_conv_kernel<<<dim3(16, 4), 256, 0, stream>>>(wv, wqkvt + (size_t)1280 * CD, CD, CNKV);
  transpose_conv_kernel<<<dim3(16, 16), 256, 0, stream>>>(wo, wot, CNQ, CD);
  gemm_qkv_rope_kernel<<<dim3(32, 12), 256, 0, stream>>>(x_b, wqkvt, fc, fs, q_b, k_b, v_t);
  flash_mfma_kernel<<<512, 256, 0, stream>>>(q_b, k_b, v_t, o_b);
  gemm_mfma_kernel<<<dim3(32, 8), 256, 0, stream>>>(o_b, wot, out, CM, CD, CNQ, CNQ);
}

// Round 13
// 127.496 us; speedup vs baseline: 1.5311x; 1.0605x over previous
//
#include <hip/hip_runtime.h>
#include <hip/hip_bf16.h>

using bf16 = __hip_bfloat16;
typedef short bf16x8 __attribute__((ext_vector_type(8)));
typedef float f32x4 __attribute__((ext_vector_type(4)));

#define CB 2
#define CS 2048
#define CD 1024
#define CH 16
#define CKH 4
#define CHD 64
#define CREP 4
#define CNQ (CH*CHD)    // 1024
#define CNKV (CKH*CHD)  // 256
#define CM (CB*CS)      // 4096

__device__ __forceinline__ unsigned short f2bf(float f) {
  union { float f; unsigned int i; } c; c.f = f;
  unsigned int r = c.i + 0x7FFFu + ((c.i >> 16) & 1u);  // RNE
  return (unsigned short)(r >> 16);
}
__device__ __forceinline__ void gload_lds16(const void* g, void* l) {
  __builtin_amdgcn_global_load_lds(
      (const __attribute__((address_space(1))) void*)g,
      (__attribute__((address_space(3))) void*)l, 16, 0, 0);
}

// ---------------------------------------------------------------------------
// bf16 MFMA GEMM v2 (R8-proven): C[M,N] f32 = A[M,K](lda) · Bt[N,K]^T.
// 128x128, BK=32, dbuf LDS, counted vmcnt. Used for the o-projection.
// ---------------------------------------------------------------------------
__global__ __launch_bounds__(256) void gemm_mfma_kernel(
    const bf16* __restrict__ A, const bf16* __restrict__ Bt,
    float* __restrict__ C, int Mm, int Nn, int Kk, int lda)
{
  __shared__ __align__(16) bf16 As[2][128 * 32];
  __shared__ __align__(16) bf16 Bs[2][128 * 32];
  const int tid = threadIdx.x;
  const int lane = tid & 63;
  const int l15 = lane & 15;
  const int g = lane >> 4;
  const int wid = tid >> 6;
  const int wr = (wid >> 1) * 64;
  const int wc = (wid & 1) * 64;
  const int m0 = blockIdx.x * 128;
  const int n0 = blockIdx.y * 128;

  f32x4 acc[4][4];
  #pragma unroll
  for (int i = 0; i < 4; ++i)
    #pragma unroll
    for (int j = 0; j < 4; ++j)
      acc[i][j] = (f32x4){0.f, 0.f, 0.f, 0.f};

  const int sr = tid >> 2;
  const int sc = (tid & 3) * 8;
  const bf16* aSrc = A + (size_t)(m0 + sr) * lda + sc;
  const bf16* bSrc = Bt + (size_t)(n0 + sr) * Kk + sc;
  const int sOff = (tid & 192) * 8;

#define GSTAGE(bi, k0) do {                                             \
    gload_lds16(aSrc + (k0),                     &As[bi][sOff]);        \
    gload_lds16(aSrc + 64 * (size_t)lda + (k0),  &As[bi][sOff + 2048]); \
    gload_lds16(bSrc + (k0),                     &Bs[bi][sOff]);        \
    gload_lds16(bSrc + 64 * (size_t)Kk + (k0),   &Bs[bi][sOff + 2048]); \
  } while (0)

  const int nt = Kk >> 5;
  int bi = 0;
  GSTAGE(0, 0);
  for (int t = 0; t < nt; ++t) {
    if (t + 1 < nt) {
      GSTAGE(bi ^ 1, (t + 1) * 32);
      asm volatile("s_waitcnt vmcnt(4)" ::: "memory");
    } else {
      asm volatile("s_waitcnt vmcnt(0)" ::: "memory");
    }
    __builtin_amdgcn_s_barrier();
    asm volatile("" ::: "memory");

    bf16x8 af[4], bfr[4];
    #pragma unroll
    for (int mt = 0; mt < 4; ++mt)
      af[mt] = *(const bf16x8*)&As[bi][(wr + mt * 16 + l15) * 32 + g * 8];
    #pragma unroll
    for (int nt2 = 0; nt2 < 4; ++nt2)
      bfr[nt2] = *(const bf16x8*)&Bs[bi][(wc + nt2 * 16 + l15) * 32 + g * 8];
    #pragma unroll
    for (int mt = 0; mt < 4; ++mt)
      #pragma unroll
      for (int nt2 = 0; nt2 < 4; ++nt2)
        acc[mt][nt2] = __builtin_amdgcn_mfma_f32_16x16x32_bf16(af[mt], bfr[nt2], acc[mt][nt2], 0, 0, 0);

    asm volatile("" ::: "memory");
    __builtin_amdgcn_s_barrier();
    bi ^= 1;
  }
#undef GSTAGE

  #pragma unroll
  for (int mt = 0; mt < 4; ++mt)
    #pragma unroll
    for (int r4 = 0; r4 < 4; ++r4) {
      const size_t row = (size_t)(m0 + wr + mt * 16 + 4 * g + r4);
      #pragma unroll
      for (int nt2 = 0; nt2 < 4; ++nt2)
        C[row * Nn + n0 + wc + nt2 * 16 + l15] = acc[mt][nt2][r4];
    }
}

// ---------------------------------------------------------------------------
// qkv GEMM with fused RoPE + layout epilogue (R12-proven).
// ---------------------------------------------------------------------------
__global__ __launch_bounds__(256) void gemm_qkv_rope_kernel(
    const bf16* __restrict__ A, const bf16* __restrict__ Bt,
    const float* __restrict__ fc, const float* __restrict__ fs,
    bf16* __restrict__ qb, bf16* __restrict__ kb, bf16* __restrict__ vt)
{
  __shared__ __align__(16) bf16 As[2][128 * 32];
  __shared__ __align__(16) bf16 Bs[2][128 * 32];
  const int tid = threadIdx.x;
  const int lane = tid & 63;
  const int l15 = lane & 15;
  const int g = lane >> 4;
  const int wid = tid >> 6;
  const int wr = (wid >> 1) * 64;
  const int wc = (wid & 1) * 64;
  const int m0 = blockIdx.x * 128;
  const int n0 = blockIdx.y * 128;
  const int Kk = CD;

  f32x4 acc[4][4];
  #pragma unroll
  for (int i = 0; i < 4; ++i)
    #pragma unroll
    for (int j = 0; j < 4; ++j)
      acc[i][j] = (f32x4){0.f, 0.f, 0.f, 0.f};

  const int sr = tid >> 2;
  const int sc = (tid & 3) * 8;
  const bf16* aSrc = A + (size_t)(m0 + sr) * Kk + sc;
  const bf16* bSrc = Bt + (size_t)(n0 + sr) * Kk + sc;
  const int sOff = (tid & 192) * 8;

#define GSTAGE(bi, k0) do {                                             \
    gload_lds16(aSrc + (k0),                     &As[bi][sOff]);        \
    gload_lds16(aSrc + 64 * (size_t)Kk + (k0),   &As[bi][sOff + 2048]); \
    gload_lds16(bSrc + (k0),                     &Bs[bi][sOff]);        \
    gload_lds16(bSrc + 64 * (size_t)Kk + (k0),   &Bs[bi][sOff + 2048]); \
  } while (0)

  const int nt = Kk >> 5;
  int bi = 0;
  GSTAGE(0, 0);
  for (int t = 0; t < nt; ++t) {
    if (t + 1 < nt) {
      GSTAGE(bi ^ 1, (t + 1) * 32);
      asm volatile("s_waitcnt vmcnt(4)" ::: "memory");
    } else {
      asm volatile("s_waitcnt vmcnt(0)" ::: "memory");
    }
    __builtin_amdgcn_s_barrier();
    asm volatile("" ::: "memory");

    bf16x8 af[4], bfr[4];
    #pragma unroll
    for (int mt = 0; mt < 4; ++mt)
      af[mt] = *(const bf16x8*)&As[bi][(wr + mt * 16 + l15) * 32 + g * 8];
    #pragma unroll
    for (int nt2 = 0; nt2 < 4; ++nt2)
      bfr[nt2] = *(const bf16x8*)&Bs[bi][(wc + nt2 * 16 + l15) * 32 + g * 8];
    #pragma unroll
    for (int mt = 0; mt < 4; ++mt)
      #pragma unroll
      for (int nt2 = 0; nt2 < 4; ++nt2)
        acc[mt][nt2] = __builtin_amdgcn_mfma_f32_16x16x32_bf16(af[mt], bfr[nt2], acc[mt][nt2], 0, 0, 0);

    asm volatile("" ::: "memory");
    __builtin_amdgcn_s_barrier();
    bi ^= 1;
  }
#undef GSTAGE

  if (blockIdx.y < 10) {
    const bool isq = (blockIdx.y < 8);
    #pragma unroll
    for (int mt = 0; mt < 4; ++mt)
      #pragma unroll
      for (int r4 = 0; r4 < 4; ++r4) {
        int m = m0 + wr + mt * 16 + 4 * g + r4;
        int s = m & (CS - 1), bb = m >> 11;
        #pragma unroll
        for (int nt2 = 0; nt2 < 4; ++nt2) {
          int n = n0 + wc + nt2 * 16 + l15;
          int d = n & 63;
          float val = acc[mt][nt2][r4];
          float par = __shfl_xor(val, 1, 64);
          float cv = fc[s * 32 + (d >> 1)];
          float sv = fs[s * 32 + (d >> 1)];
          float o = (d & 1) ? (par * sv + val * cv) : (val * cv - par * sv);
          if (isq) {
            int h = n >> 6;
            ((unsigned short*)qb)[(((size_t)bb * CH + h) * CS + s) * CHD + d] = f2bf(o);
          } else {
            int kh = (n >> 6) - 16;
            ((unsigned short*)kb)[(((size_t)bb * CKH + kh) * CS + s) * CHD + d] = f2bf(o);
          }
        }
      }
  } else {
    #pragma unroll
    for (int mt = 0; mt < 4; ++mt) {
      int mb = m0 + wr + mt * 16 + 4 * g;
      int s0 = mb & (CS - 1), bb = mb >> 11;
      #pragma unroll
      for (int nt2 = 0; nt2 < 4; ++nt2) {
        int n = n0 + wc + nt2 * 16 + l15;
        int d = n & 63;
        int kh = (n >> 6) - 20;
        ushort4 pk = make_ushort4(f2bf(acc[mt][nt2][0]), f2bf(acc[mt][nt2][1]),
                                  f2bf(acc[mt][nt2][2]), f2bf(acc[mt][nt2][3]));
        *(ushort4*)&((unsigned short*)vt)[(((size_t)bb * CKH + kh) * CHD + d) * CS + s0] = pk;
      }
    }
  }
}

// ---------------------------------------------------------------------------
// Merged prep: conv_x (blocks 0..2047) + 4 weight transposes (2048..2687).
// Bodies identical to the R12-proven conv_x / transpose_conv kernels.
// ---------------------------------------------------------------------------
__global__ __launch_bounds__(256) void prep_kernel(
    const float* __restrict__ x, bf16* __restrict__ xb,
    const float* __restrict__ wq, const float* __restrict__ wk,
    const float* __restrict__ wv, const float* __restrict__ wo,
    bf16* __restrict__ wqkvt, bf16* __restrict__ wot)
{
  const int tid = threadIdx.x;
  int bid = blockIdx.x;
  if (bid < 2048) {
    int i = (bid * 256 + tid) * 8;
    float4 a = *(const float4*)&x[i];
    float4 b = *(const float4*)&x[i + 4];
    unsigned short* o = (unsigned short*)xb + i;
    *(ushort4*)o = make_ushort4(f2bf(a.x), f2bf(a.y), f2bf(a.z), f2bf(a.w));
    *(ushort4*)(o + 4) = make_ushort4(f2bf(b.x), f2bf(b.y), f2bf(b.z), f2bf(b.w));
    return;
  }
  bid -= 2048;
  const float* W; bf16* Wt; int Nn, bx, by;
  if (bid < 256)      { W = wq; Wt = wqkvt;                      Nn = 1024; bx = bid & 15;        by = bid >> 4; }
  else if (bid < 320) { W = wk; Wt = wqkvt + (size_t)1024 * CD;  Nn = 256;  bx = (bid-256) & 15;  by = (bid-256) >> 4; }
  else if (bid < 384) { W = wv; Wt = wqkvt + (size_t)1280 * CD;  Nn = 256;  bx = (bid-320) & 15;  by = (bid-320) >> 4; }
  else                { W = wo; Wt = wot;                        Nn = 1024; bx = (bid-384) & 15;  by = (bid-384) >> 4; }
  const int Kk = 1024;
  const int k0 = bx * 64;
  const int n0 = by * 64;

  __shared__ float T[64][65];
  const int lr = tid >> 4;
  const int lc = (tid & 15) * 4;
  #pragma unroll
  for (int i = 0; i < 4; ++i) {
    float4 v = *(const float4*)&W[(size_t)(k0 + lr + i * 16) * Nn + n0 + lc];
    T[lr + i * 16][lc + 0] = v.x;
    T[lr + i * 16][lc + 1] = v.y;
    T[lr + i * 16][lc + 2] = v.z;
    T[lr + i * 16][lc + 3] = v.w;
  }
  __syncthreads();
  const int rn = tid >> 3;
  const int ck = (tid & 7) * 8;
  #pragma unroll
  for (int i = 0; i < 2; ++i) {
    int nn = rn + i * 32;
    unsigned short u[8];
    #pragma unroll
    for (int e = 0; e < 8; ++e) u[e] = f2bf(T[ck + e][nn]);
    unsigned short* dst = (unsigned short*)Wt + (size_t)(n0 + nn) * Kk + k0 + ck;
    *(ushort4*)dst = make_ushort4(u[0], u[1], u[2], u[3]);
    *(ushort4*)(dst + 4) = make_ushort4(u[4], u[5], u[6], u[7]);
  }
}

// ---------------------------------------------------------------------------
// MFMA flash attention (R8-proven body). ONLY change: complementary qt
// pairing — under round-robin dispatch CU c hosts blocks c and c+256; the
// old monotone map gave them 48 vs 18 tiles (2.7x static imbalance, measured
// tau=1.24us/tile fits R8=48tau and R11=64tau). New map pairs qt and 63-qt
// so every CU carries ~33.5 tiles.
// ---------------------------------------------------------------------------
__global__ __launch_bounds__(256, 2) void flash_mfma_kernel(
    const bf16* __restrict__ qb, const bf16* __restrict__ kb,
    const bf16* __restrict__ vt, bf16* __restrict__ ob)
{
  __shared__ __align__(16) char arena[51200];
  char* KL = arena;                       // [2][8192]: K tile 64x(64 bf16)
  char* VL = arena + 16384;               // [2][8192]: V^T tile 64x(64 bf16)
  const int tid = threadIdx.x;
  const int lane = tid & 63;
  const int wid = tid >> 6;
  unsigned short* PLW = (unsigned short*)(arena + 32768) + wid * 2304; // [32][72]
  const int l15 = lane & 15;
  const int g = lane >> 4;
  const int blk = blockIdx.x;
  const int grp = blk & 7;                // b*4+kh
  const int idx = blk >> 3;               // 0..63
  const int qt = (idx < 32) ? (63 - idx) : (idx - 32);  // complementary pairs
  const int kh = grp & 3;
  const int b = grp >> 2;
  const int h = kh * CREP + wid;
  const int N64 = (qt >> 1) + 1;
  const float SC = 0.18033688f;           // 0.125 * log2(e)

  const bf16* qbase = qb + ((size_t)(b * CH + h) * CS + qt * 32) * CHD;
  const bf16* kbase = kb + (size_t)(b * CKH + kh) * CS * CHD;
  const bf16* vbase = vt + (size_t)(b * CKH + kh) * CHD * CS;  // [d][s]

  bf16x8 qf[2][2];
  #pragma unroll
  for (int qs = 0; qs < 2; ++qs)
    #pragma unroll
    for (int c = 0; c < 2; ++c)
      qf[qs][c] = *(const bf16x8*)(qbase + (qs * 16 + l15) * CHD + c * 32 + g * 8);

  bf16x8 ones;
  #pragma unroll
  for (int e = 0; e < 8; ++e) ones[e] = (short)0x3F80;  // bf16 1.0

  f32x4 oacc[2][4];
  f32x4 lacc[2];
  #pragma unroll
  for (int qs = 0; qs < 2; ++qs) {
    lacc[qs] = (f32x4){0.f, 0.f, 0.f, 0.f};
    #pragma unroll
    for (int dt = 0; dt < 4; ++dt)
      oacc[qs][dt] = (f32x4){0.f, 0.f, 0.f, 0.f};
  }
  float mrow[2] = {-1e30f, -1e30f};

  const int slr = tid >> 3;
  const int scg = (tid & 7) ^ (slr & 7);
  const bf16* kstage = kbase + (size_t)slr * CHD + scg * 8;
  const bf16* vstage = vbase + (size_t)slr * CS + scg * 8;
  char* kdst = KL + wid * 1024;
  char* vdst = VL + wid * 1024;

#define STAGE(bi, t64) do {                                        \
    const bf16* ks_ = kstage + (size_t)(t64) * 64 * CHD;           \
    const bf16* vs_ = vstage + (t64) * 64;                         \
    gload_lds16(ks_,            kdst + (bi) * 8192);               \
    gload_lds16(ks_ + 32 * CHD, kdst + (bi) * 8192 + 4096);        \
    gload_lds16(vs_,            vdst + (bi) * 8192);               \
    gload_lds16(vs_ + 32 * CS,  vdst + (bi) * 8192 + 4096);        \
  } while (0)

  int bi = 0;
  STAGE(0, 0);
  for (int t = 0; t < N64; ++t) {
    if (t + 1 < N64) {
      STAGE(bi ^ 1, t + 1);
      asm volatile("s_waitcnt vmcnt(4)" ::: "memory");
    } else {
      asm volatile("s_waitcnt vmcnt(0)" ::: "memory");
    }
    __builtin_amdgcn_s_barrier();
    asm volatile("" ::: "memory");

    const char* KB = KL + bi * 8192;
    const char* VB = VL + bi * 8192;
    bf16x8 kfr[4][2], vfr[4][2];
    #pragma unroll
    for (int kt = 0; kt < 4; ++kt) {
      int row = kt * 16 + l15;
      #pragma unroll
      for (int c = 0; c < 2; ++c)
        kfr[kt][c] = *(const bf16x8*)(KB + row * 128 + (((c * 4 + g) ^ (row & 7)) << 4));
    }
    #pragma unroll
    for (int dt = 0; dt < 4; ++dt) {
      int row = dt * 16 + l15;
      #pragma unroll
      for (int st = 0; st < 2; ++st)
        vfr[dt][st] = *(const bf16x8*)(VB + row * 128 + (((st * 4 + g) ^ (row & 7)) << 4));
    }

    // QK^T (swapped): S^T[k][q]
    f32x4 sacc[4][2];
    #pragma unroll
    for (int kt = 0; kt < 4; ++kt)
      #pragma unroll
      for (int qs = 0; qs < 2; ++qs)
        sacc[kt][qs] = (f32x4){0.f, 0.f, 0.f, 0.f};
    #pragma unroll
    for (int c = 0; c < 2; ++c)
      #pragma unroll
      for (int kt = 0; kt < 4; ++kt)
        #pragma unroll
        for (int qs = 0; qs < 2; ++qs)
          sacc[kt][qs] = __builtin_amdgcn_mfma_f32_16x16x32_bf16(kfr[kt][c], qf[qs][c], sacc[kt][qs], 0, 0, 0);

    const bool diag = (t == N64 - 1);
    #pragma unroll
    for (int qs = 0; qs < 2; ++qs) {
      float e[16];
      float pm = -1e30f;
      #pragma unroll
      for (int kt = 0; kt < 4; ++kt)
        #pragma unroll
        for (int r = 0; r < 4; ++r) {
          float v = sacc[kt][qs][r] * SC;
          if (diag) {
            int koff = t * 64 + kt * 16 + 4 * g + r;
            if (koff > qt * 32 + qs * 16 + l15) v = -1e30f;
          }
          e[kt * 4 + r] = v;
          pm = fmaxf(pm, v);
        }
      if (__any(pm > mrow[qs] + 8.0f)) {       // slow path: exact rescale
        pm = fmaxf(pm, __shfl_xor(pm, 16, 64));
        pm = fmaxf(pm, __shfl_xor(pm, 32, 64));
        float nm = fmaxf(mrow[qs], pm);
        float corr = exp2f(mrow[qs] - nm);
        mrow[qs] = nm;
        lacc[qs] *= corr;
        #pragma unroll
        for (int dt = 0; dt < 4; ++dt) oacc[qs][dt] *= corr;
      }
      unsigned short pb[16];
      #pragma unroll
      for (int i = 0; i < 16; ++i)
        pb[i] = f2bf(exp2f(e[i] - mrow[qs]));  // p <= 2^8
      #pragma unroll
      for (int kt = 0; kt < 4; ++kt)
        *(ushort4*)&PLW[(qs * 16 + l15) * 72 + kt * 16 + 4 * g] =
            make_ushort4(pb[kt * 4 + 0], pb[kt * 4 + 1], pb[kt * 4 + 2], pb[kt * 4 + 3]);
    }

    // PV + psum (same-wave LDS RAW)
    #pragma unroll
    for (int qs = 0; qs < 2; ++qs) {
      #pragma unroll
      for (int st = 0; st < 2; ++st) {
        bf16x8 pf = *(const bf16x8*)&PLW[(qs * 16 + l15) * 72 + st * 32 + g * 8];
        lacc[qs] = __builtin_amdgcn_mfma_f32_16x16x32_bf16(ones, pf, lacc[qs], 0, 0, 0);
        #pragma unroll
        for (int dt = 0; dt < 4; ++dt)
          oacc[qs][dt] = __builtin_amdgcn_mfma_f32_16x16x32_bf16(vfr[dt][st], pf, oacc[qs][dt], 0, 0, 0);
      }
    }

    asm volatile("" ::: "memory");
    __builtin_amdgcn_s_barrier();
    bi ^= 1;
  }
#undef STAGE

  #pragma unroll
  for (int qs = 0; qs < 2; ++qs) {
    float inv = 1.0f / lacc[qs][0];
    int qg = qt * 32 + qs * 16 + l15;
    unsigned short* orow = (unsigned short*)ob + (size_t)(b * CS + qg) * CNQ + h * CHD;
    #pragma unroll
    for (int dt = 0; dt < 4; ++dt) {
      *(ushort4*)&orow[dt * 16 + 4 * g] =
          make_ushort4(f2bf(oacc[qs][dt][0] * inv), f2bf(oacc[qs][dt][1] * inv),
                       f2bf(oacc[qs][dt][2] * inv), f2bf(oacc[qs][dt][3] * inv));
    }
  }
}

// ---------------------------------------------------------------------------
extern "C" void kernel_launch(void* const* d_in, const int* in_sizes, int n_in,
                              void* d_out, int out_size, void* d_ws, size_t ws_size,
                              hipStream_t stream)
{
  const float* x  = (const float*)d_in[0];
  const float* wq = (const float*)d_in[1];
  const float* wk = (const float*)d_in[2];
  const float* wv = (const float*)d_in[3];
  const float* wo = (const float*)d_in[4];
  const float* fc = (const float*)d_in[5];
  const float* fs = (const float*)d_in[6];
  float* out = (float*)d_out;

  char* ws = (char*)d_ws;
  // workspace (peak 34.6MB, no aliasing):
  bf16*  x_b   = (bf16*)(ws);                 // [0, 8M)
  bf16*  wqkvt = (bf16*)(ws + 8388608);       // [8M, 11M)   1536x1024 bf16
  bf16*  wot   = (bf16*)(ws + 11534336);      // [11M, 13M)  1024x1024 bf16
  bf16*  q_b   = (bf16*)(ws + 13631488);      // [13M, 21M)  [B,H,S,HD]
  bf16*  k_b   = (bf16*)(ws + 22020096);      // [21M, 23M)  [B,KH,S,HD]
  bf16*  v_t   = (bf16*)(ws + 24117248);      // [23M, 25M)  [B,KH,HD,S]
  bf16*  o_b   = (bf16*)(ws + 26214400);      // [25M, 33M)

  prep_kernel<<<2688, 256, 0, stream>>>(x, x_b, wq, wk, wv, wo, wqkvt, wot);
  gemm_qkv_rope_kernel<<<dim3(32, 12), 256, 0, stream>>>(x_b, wqkvt, fc, fs, q_b, k_b, v_t);
  flash_mfma_kernel<<<512, 256, 0, stream>>>(q_b, k_b, v_t, o_b);
  gemm_mfma_kernel<<<dim3(32, 8), 256, 0, stream>>>(o_b, wot, out, CM, CD, CNQ, CNQ);
}